// Round 3
// baseline (220.517 us; speedup 1.0000x reference)
//
#include <hip/hip_runtime.h>
#include <hip/hip_bf16.h>

#define EMB 768
#define NH 8
#define DH 96
#define BATCH 8
#define SEQ 1024
#define M_TOT (BATCH * SEQ)   // 8192 rows of x
#define NCOLS (3 * EMB)       // q(768) | k(768) | v(768) output channels

typedef float f32x4 __attribute__((ext_vector_type(4)));
typedef __bf16 bf16x8 __attribute__((ext_vector_type(8)));

__device__ __forceinline__ unsigned short f2bf_bits(float f) {
  __hip_bfloat16 b = __float2bfloat16(f);
  return *reinterpret_cast<unsigned short*>(&b);
}

__device__ __forceinline__ void gload_lds16(const void* g, void* l) {
  // async global->LDS, 16B per lane; LDS dest must be wave-uniform base (+lane*16 by HW)
  __builtin_amdgcn_global_load_lds(
      (__attribute__((address_space(1))) void*)(g),
      (__attribute__((address_space(3))) void*)(l), 16, 0, 0);
}

// ---------------- prep: x fp32 -> bf16 ----------------
__global__ void prep_x_kernel(const float* __restrict__ x, __hip_bfloat16* __restrict__ xb) {
  const int n4 = M_TOT * EMB / 4;
  int i = blockIdx.x * blockDim.x + threadIdx.x;
  if (i < n4) {
    f32x4 v = reinterpret_cast<const f32x4*>(x)[i];
    ushort4 o;
    o.x = f2bf_bits(v[0]);
    o.y = f2bf_bits(v[1]);
    o.z = f2bf_bits(v[2]);
    o.w = f2bf_bits(v[3]);
    reinterpret_cast<ushort4*>(xb)[i] = o;
  }
}

// ---------------- prep: permuted weights -> bf16, bias fp32 ----------------
__global__ void prep_w_kernel(const float* __restrict__ qkv_w, const float* __restrict__ qkv_b,
                              const float* __restrict__ val_w, const float* __restrict__ val_b,
                              __hip_bfloat16* __restrict__ Wall, float* __restrict__ bias) {
  const float inv_s = 0.03608439182435161f;  // 1/sqrt(768)
  int idx = blockIdx.x * 256 + threadIdx.x;
  if (idx >= NCOLS * EMB) return;
  int r = idx / EMB;
  int c = idx - r * EMB;
  float v;
  if (r < EMB) {
    int h = r / DH, d = r - h * DH;
    int src = h * 192 + 2 * d;
    v = qkv_w[(size_t)src * EMB + c] * inv_s;
    if (c == 0) bias[r] = qkv_b[src] * inv_s;
  } else if (r < 2 * EMB) {
    int r2 = r - EMB;
    int h = r2 / DH, d = r2 - h * DH;
    int src = h * 192 + 2 * d + 1;
    v = qkv_w[(size_t)src * EMB + c];
    if (c == 0) bias[r] = qkv_b[src];
  } else {
    int r3 = r - 2 * EMB;
    v = val_w[(size_t)r3 * EMB + c];
    if (c == 0) bias[r] = val_b[r3];
  }
  Wall[idx] = __float2bfloat16(v);
}

// ---------------- fused projection GEMM (m97-structure, 128x128, BK=32) ----------------
__global__ __launch_bounds__(256) void gemm_kernel(
    const __hip_bfloat16* __restrict__ xb, const __hip_bfloat16* __restrict__ Wall,
    const float* __restrict__ bias, __hip_bfloat16* __restrict__ q_ws,
    __hip_bfloat16* __restrict__ k_ws, float* __restrict__ vout) {
  __shared__ __hip_bfloat16 As[128 * 32];
  __shared__ __hip_bfloat16 Bs[128 * 32];
  const int tid = threadIdx.x;
  const int w = tid >> 6, l = tid & 63;
  const int m0 = blockIdx.x * 128;
  const int n0 = blockIdx.y * 128;
  const int wr = w >> 1, wc = w & 1;

  f32x4 acc[4][4] = {};

  const int sr0 = (w * 2 + 0) * 16 + (l >> 2);
  const int sr1 = (w * 2 + 1) * 16 + (l >> 2);
  const int sc = (l & 3) * 8;

  for (int kt = 0; kt < EMB / 32; ++kt) {
    const int k0 = kt * 32;
    gload_lds16(xb + (size_t)(m0 + sr0) * EMB + k0 + sc, (void*)(As + (w * 2 + 0) * 512));
    gload_lds16(xb + (size_t)(m0 + sr1) * EMB + k0 + sc, (void*)(As + (w * 2 + 1) * 512));
    gload_lds16(Wall + (size_t)(n0 + sr0) * EMB + k0 + sc, (void*)(Bs + (w * 2 + 0) * 512));
    gload_lds16(Wall + (size_t)(n0 + sr1) * EMB + k0 + sc, (void*)(Bs + (w * 2 + 1) * 512));
    __syncthreads();

    bf16x8 af[4], bfr[4];
#pragma unroll
    for (int t = 0; t < 4; ++t) {
      af[t] = *reinterpret_cast<const bf16x8*>(As + (wr * 64 + t * 16 + (l & 15)) * 32 + (l >> 4) * 8);
      bfr[t] = *reinterpret_cast<const bf16x8*>(Bs + (wc * 64 + t * 16 + (l & 15)) * 32 + (l >> 4) * 8);
    }
#pragma unroll
    for (int i = 0; i < 4; ++i)
#pragma unroll
      for (int j = 0; j < 4; ++j)
        acc[i][j] = __builtin_amdgcn_mfma_f32_16x16x32_bf16(af[i], bfr[j], acc[i][j], 0, 0, 0);
    __syncthreads();
  }

  const int rowbase = m0 + wr * 64;
  const int colbase = n0 + wc * 64;
#pragma unroll
  for (int j = 0; j < 4; ++j) {
    const int n = colbase + j * 16 + (l & 15);
    const float bb = bias[n];
#pragma unroll
    for (int i = 0; i < 4; ++i) {
#pragma unroll
      for (int q = 0; q < 4; ++q) {
        const int m = rowbase + i * 16 + (l >> 4) * 4 + q;
        const float v = acc[i][j][q] + bb;
        if (n0 >= 2 * EMB) {
          vout[(size_t)m * EMB + (n - 2 * EMB)] = v;
        } else if (n0 >= EMB) {
          k_ws[(size_t)m * EMB + (n - EMB)] = __float2bfloat16(v);
        } else {
          q_ws[(size_t)m * EMB + n] = __float2bfloat16(v);
        }
      }
    }
  }
}

// ---------------- fused QK^T + softmax, swapped-operand MFMA ----------------
// grid (SEQ/16, BATCH*NH); 256 threads = 4 waves. Block: 16 q-rows x 1024 k-cols.
// mfma(K_frag, Q_frag): D col = lane&15 -> q-row, D row = (lane>>4)*4+reg -> k.
// So lane (lr,lc) holds acc[ct][j] = score(q = row0+lc, k = w*256 + ct*16 + lr*4 + j)
// -> 4 consecutive k-columns per lane -> f32x4 rel reads and energy writes.
__global__ __launch_bounds__(256) void attn_kernel(
    const __hip_bfloat16* __restrict__ q_ws, const __hip_bfloat16* __restrict__ k_ws,
    const float* __restrict__ rel, float* __restrict__ eout) {
  __shared__ float redmax[16][4];
  __shared__ float redsum[16][4];
  const int tid = threadIdx.x;
  const int w = tid >> 6, l = tid & 63;
  const int rb = blockIdx.x;
  const int bh = blockIdx.y;
  const int b = bh >> 3, h = bh & 7;
  const int row0 = rb * 16;
  const int lr = l >> 4;   // k sub-group 0..3
  const int lc = l & 15;   // q-row within tile

  // ---- Q fragments (B-operand): q-row = row0+lc, pre-scaled by 1/sqrt(768) ----
  const __hip_bfloat16* qbase = q_ws + ((size_t)(b * SEQ + row0 + lc)) * EMB + h * DH;
  bf16x8 qf[3];
#pragma unroll
  for (int kc = 0; kc < 3; ++kc)
    qf[kc] = *reinterpret_cast<const bf16x8*>(qbase + kc * 32 + lr * 8);

  // ---- QK^T into registers (A-operand = K rows) ----
  const __hip_bfloat16* kbase = k_ws + ((size_t)(b * SEQ + w * 256 + lc)) * EMB + h * DH;
  f32x4 acc[16];
  __builtin_amdgcn_s_setprio(1);
#pragma unroll
  for (int ct = 0; ct < 16; ++ct) {
    const __hip_bfloat16* kb = kbase + (size_t)(ct * 16) * EMB;
    f32x4 a = {0.f, 0.f, 0.f, 0.f};
#pragma unroll
    for (int kc = 0; kc < 3; ++kc) {
      bf16x8 kf = *reinterpret_cast<const bf16x8*>(kb + kc * 32 + lr * 8);
      a = __builtin_amdgcn_mfma_f32_16x16x32_bf16(kf, qf[kc], a, 0, 0, 0);
    }
    acc[ct] = a;
  }
  __builtin_amdgcn_s_setprio(0);

  // ---- add rel_pos (f32x4), per-row max ----
  const float* relp = rel + ((size_t)h * SEQ + row0 + lc) * SEQ + w * 256 + lr * 4;
  float mx = -3.4e38f;
#pragma unroll
  for (int ct = 0; ct < 16; ++ct) {
    f32x4 r = *reinterpret_cast<const f32x4*>(relp + ct * 16);
    acc[ct] = acc[ct] + r;
    mx = fmaxf(mx, fmaxf(fmaxf(acc[ct][0], acc[ct][1]), fmaxf(acc[ct][2], acc[ct][3])));
  }
  // combine the 4 lr-groups (same q-row lc) within the wave
  mx = fmaxf(mx, __shfl_xor(mx, 16));
  mx = fmaxf(mx, __shfl_xor(mx, 32));
  if (l < 16) redmax[lc][w] = mx;
  __syncthreads();
  {
    const float* rm = redmax[lc];
    mx = fmaxf(fmaxf(rm[0], rm[1]), fmaxf(rm[2], rm[3]));
  }

  // ---- exp, per-row sum ----
  float sm = 0.f;
#pragma unroll
  for (int ct = 0; ct < 16; ++ct) {
#pragma unroll
    for (int j = 0; j < 4; ++j) {
      float e = __expf(acc[ct][j] - mx);
      acc[ct][j] = e;
      sm += e;
    }
  }
  sm += __shfl_xor(sm, 16);
  sm += __shfl_xor(sm, 32);
  if (l < 16) redsum[lc][w] = sm;
  __syncthreads();
  float rinv;
  {
    const float* rs = redsum[lc];
    rinv = 1.0f / (rs[0] + rs[1] + rs[2] + rs[3]);
  }

  // ---- normalized f32x4 write ----
  float* op = eout + ((size_t)bh * SEQ + row0 + lc) * SEQ + w * 256 + lr * 4;
#pragma unroll
  for (int ct = 0; ct < 16; ++ct) {
    f32x4 v = acc[ct] * rinv;
    *reinterpret_cast<f32x4*>(op + ct * 16) = v;
  }
}

extern "C" void kernel_launch(void* const* d_in, const int* in_sizes, int n_in,
                              void* d_out, int out_size, void* d_ws, size_t ws_size,
                              hipStream_t stream) {
  const float* x = (const float*)d_in[0];
  const float* rel = (const float*)d_in[1];
  const float* qkv_w = (const float*)d_in[2];
  const float* qkv_b = (const float*)d_in[3];
  const float* val_w = (const float*)d_in[4];
  const float* val_b = (const float*)d_in[5];
  float* out = (float*)d_out;

  char* ws = (char*)d_ws;
  __hip_bfloat16* xb = (__hip_bfloat16*)(ws);                  // 12,582,912
  __hip_bfloat16* Wall = (__hip_bfloat16*)(ws + 12582912);     //  3,538,944
  float* bias = (float*)(ws + 16121856);                       //      9,216
  __hip_bfloat16* q_ws = (__hip_bfloat16*)(ws + 16131072);     // 12,582,912
  __hip_bfloat16* k_ws = (__hip_bfloat16*)(ws + 28713984);     // 12,582,912

  float* vout = out;                       // [8192][768] values
  float* eout = out + (size_t)M_TOT * EMB; // [64][1024][1024] energy

  prep_x_kernel<<<dim3(M_TOT * EMB / 4 / 256), dim3(256), 0, stream>>>(x, xb);
  prep_w_kernel<<<dim3(NCOLS * EMB / 256), dim3(256), 0, stream>>>(qkv_w, qkv_b, val_w, val_b,
                                                                   Wall, bias);
  gemm_kernel<<<dim3(M_TOT / 128, NCOLS / 128), dim3(256), 0, stream>>>(xb, Wall, bias, q_ws,
                                                                        k_ws, vout);
  attn_kernel<<<dim3(SEQ / 16, BATCH * NH), dim3(256), 0, stream>>>(q_ws, k_ws, rel, eout);
}